// Round 9
// baseline (2971.870 us; speedup 1.0000x reference)
//
#include <hip/hip_runtime.h>

#define N_NODES 20000
#define N_EDGES 640000
#define XS 136   // LDS activation row stride in bf16 units (128 + 8 pad)
#define NEBLK 10000        // edge blocks
#define NODET 1250         // node tiles (16 nodes each)
#define TKTH  (NEBLK - NODET)

#define INV_SQRT_AVG 0.0070714082f   // 1/sqrt(19999)
#define INV_AVG      5.000250e-5f    // 1/19999

#define FEATB_OFF 147456             // ushort offset of bf16 feat table in ws (after 9*16384 weights)

typedef __attribute__((ext_vector_type(8))) short bf16x8;
typedef __attribute__((ext_vector_type(4))) float f32x4;
typedef __attribute__((ext_vector_type(2))) _Float16 f16x2;

// Non-draining barrier: LDS ordering only (proven neutral-correct earlier).
#define BAR() asm volatile("s_waitcnt lgkmcnt(0)\n\ts_barrier" ::: "memory")

__device__ __forceinline__ ushort f2b(float f) {
  unsigned x = __float_as_uint(f);
  unsigned r = (x + 0x7fffu + ((x >> 16) & 1u)) >> 16;   // RNE
  return (ushort)r;
}
__device__ __forceinline__ uint cvt_pk_bf16(float lo, float hi) {
  uint r;
  asm("v_cvt_pk_bf16_f32 %0, %1, %2" : "=v"(r) : "v"(lo), "v"(hi));
  return r;
}
__device__ __forceinline__ float silu(float v) {
  return v * __builtin_amdgcn_rcpf(1.0f + __expf(-v));
}
__device__ __forceinline__ float sigmoid_fast(float v) {
  return __builtin_amdgcn_rcpf(1.0f + __expf(-v));
}
__device__ __forceinline__ float b2f(ushort u) {
  return __uint_as_float(((uint)u) << 16);
}
__device__ __forceinline__ float lo16f(uint u) {
  ushort us = (ushort)(u & 0xffffu);
  _Float16 h; __builtin_memcpy(&h, &us, 2);
  return (float)h;
}
__device__ __forceinline__ float hi16f(uint u) {
  ushort us = (ushort)(u >> 16);
  _Float16 h; __builtin_memcpy(&h, &us, 2);
  return (float)h;
}
__device__ __forceinline__ ushort f2h(float x) {
  _Float16 h = (_Float16)x;
  ushort u; __builtin_memcpy(&u, &h, 2);
  return u;
}
// native packed f16 atomic add (global_atomic_pk_add_f16, gfx90a+)
__device__ __forceinline__ void pk_atomic_f16(ushort* p, float x, float y) {
  typedef __attribute__((address_space(1))) f16x2 gf2;
  f16x2 v = {(_Float16)x, (_Float16)y};
  __builtin_amdgcn_global_atomic_fadd_v2f16((gf2*)(unsigned long long)p, v);
}
// coherent read of a packed-f16 pair via atomic add of zero (returns old value)
__device__ __forceinline__ f16x2 pk_atomic_read16(const ushort* p) {
  typedef __attribute__((address_space(1))) f16x2 gf2;
  f16x2 z = {(_Float16)0.0f, (_Float16)0.0f};
  return __builtin_amdgcn_global_atomic_fadd_v2f16((gf2*)(unsigned long long)p, z);
}

// ---------------- setup ----------------
struct PrepArgs { const float* src[9]; };

__global__ __launch_bounds__(256) void setup_kernel(PrepArgs a,
                                                    const float* feat,
                                                    ushort* __restrict__ wq,
                                                    ushort* __restrict__ featb,
                                                    uint* m_acc32,
                                                    int* __restrict__ hist,
                                                    int* __restrict__ ctr,
                                                    ushort* __restrict__ ewq,
                                                    const float* __restrict__ e_w,
                                                    const float* __restrict__ px_out_w) {
  int i = blockIdx.x * 256 + threadIdx.x;          // i < 2,560,000 exactly
  float fv = feat[i];
  asm volatile("" ::: "memory");                   // feat read precedes m_acc zero
  featb[i] = f2b(fv);
  if (i < N_NODES * 64) m_acc32[i] = 0u;           // zero f16 m_acc (first 5.12 MB)
  if (i < N_NODES) hist[i] = 0;
  if (i < 8) ctr[i] = 0;                           // sync counters (in d_ws)
  if (i < 9 * 16384) {
    int m = i >> 14, idx = i & 16383;
    int k = idx >> 7, n = idx & 127;
    wq[m * 16384 + n * 128 + k] = f2b(a.src[m][k * 128 + n]);
  }
  if (i < 4096) {                                  // ew table [0,2048), pw table [2048,4096)
    int t = i >> 11, idx = i & 2047, col = idx >> 7, k = idx & 127;
    float v = (col == 0) ? (t ? px_out_w[k] : e_w[k]) : 0.0f;
    ewq[i] = f2b(v);
  }
}

// ---------------- MFMA helpers ----------------
__device__ __forceinline__ void gemm2(const ushort* X, const ushort* __restrict__ Wn0,
                                      int c, int q, f32x4 acc[4][2]) {
  const int kq = q * 8;
  bf16x8 b[2][4];
#pragma unroll
  for (int ct = 0; ct < 2; ++ct)
#pragma unroll
    for (int ks = 0; ks < 4; ++ks)
      b[ct][ks] = *(const bf16x8*)(Wn0 + (ct * 16 + c) * 128 + ks * 32 + kq);
#pragma unroll
  for (int mt = 0; mt < 4; ++mt)
#pragma unroll
    for (int ks = 0; ks < 4; ++ks) {
      bf16x8 a = *(const bf16x8*)(X + (mt * 16 + c) * XS + ks * 32 + kq);
      acc[mt][0] = __builtin_amdgcn_mfma_f32_16x16x32_bf16(a, b[0][ks], acc[mt][0], 0, 0, 0);
      acc[mt][1] = __builtin_amdgcn_mfma_f32_16x16x32_bf16(a, b[1][ks], acc[mt][1], 0, 0, 0);
    }
}

__device__ __forceinline__ void gemm1(const ushort* X, const ushort* __restrict__ Wn0,
                                      int c, int q, f32x4 acc[2]) {
  const int kq = q * 8;
#pragma unroll
  for (int ks = 0; ks < 4; ++ks) {
    bf16x8 a  = *(const bf16x8*)(X + c * XS + ks * 32 + kq);
    bf16x8 b0 = *(const bf16x8*)(Wn0 + c * 128 + ks * 32 + kq);
    bf16x8 b1 = *(const bf16x8*)(Wn0 + (16 + c) * 128 + ks * 32 + kq);
    acc[0] = __builtin_amdgcn_mfma_f32_16x16x32_bf16(a, b0, acc[0], 0, 0, 0);
    acc[1] = __builtin_amdgcn_mfma_f32_16x16x32_bf16(a, b1, acc[1], 0, 0, 0);
  }
}

// per-wave 16-row x 1-col dot (table col0 only nonzero; result on c==0 lanes)
__device__ __forceinline__ void gemm_dot16(const ushort* X, const ushort* __restrict__ T,
                                           int c, int q, f32x4* accd) {
  const int kq = q * 8;
#pragma unroll
  for (int ks = 0; ks < 4; ++ks) {
    bf16x8 bg = *(const bf16x8*)(T + c * 128 + ks * 32 + kq);
    bf16x8 a = *(const bf16x8*)(X + c * XS + ks * 32 + kq);
    *accd = __builtin_amdgcn_mfma_f32_16x16x32_bf16(a, bg, *accd, 0, 0, 0);
  }
}

__device__ __forceinline__ void stage_row16(ushort* X, const ushort* __restrict__ src,
                                            int row, int sub) {
  const bf16x8* s = (const bf16x8*)src;
  ((bf16x8*)(X + row * XS))[sub] = s[sub];
}

// ---------------- megaprep: precompute (blocks 0..1249) || sort (blocks 1250..6249) ----
// Sort role is fully work-stealing (deadlock-free at any residency): hist chunks via
// ticket ctr[0], chunk-completion count ctr[1]; the block completing the 2500th chunk
// runs the 20000-bin scan alone, sets ctr[2]; all sort blocks then steal scatter
// chunks via ctr[3].
__global__ __launch_bounds__(256, 8) void megaprep_kernel(
    const int* __restrict__ snd, const int* __restrict__ rcv,
    int* __restrict__ hist, int* __restrict__ cursor,
    uint* __restrict__ sedge, int* ctr,
    const ushort* __restrict__ featb, const ushort* __restrict__ wq,
    const float* __restrict__ pe_b0,
    ushort* __restrict__ p0h, ushort* __restrict__ p1h,
    float* __restrict__ outv) {
  const int tid = threadIdx.x;

  if (blockIdx.x < 1250) {
    // ---- precompute role: 16 nodes/block ----
    __shared__ ushort XA[16 * XS];
    const int pblk = blockIdx.x;
    const int nb0 = pblk * 16;
    const int lane = tid & 63;
    const int wv = tid >> 6;
    const int c = lane & 15, q = lane >> 4;
    const int n0 = wv * 32;
    const int col0 = n0 + c, col1 = col0 + 16;

    int gid = pblk * 256 + tid;                    // 1250*256 = 320000 >= 60000
    if (gid < 60000) outv[gid] = 0.0f;

    {
      int row = tid >> 4, sub = tid & 15;
      stage_row16(XA, featb + (size_t)(nb0 + row) * 128, row, sub);
    }
    BAR();

    const f32x4 z4 = {0.f, 0.f, 0.f, 0.f};
    f32x4 a2[2];
    a2[0] = z4; a2[1] = z4;
    gemm1(XA, wq + 0 * 16384 + n0 * 128, c, q, a2);
#pragma unroll
    for (int rg = 0; rg < 4; ++rg) {
      int nn = nb0 + q * 4 + rg;
      p0h[(size_t)nn * 128 + col0] = f2h(a2[0][rg]);
      p0h[(size_t)nn * 128 + col1] = f2h(a2[1][rg]);
    }
    a2[0] = z4; a2[1] = z4;
    gemm1(XA, wq + 1 * 16384 + n0 * 128, c, q, a2);
    float bb0 = pe_b0[col0], bb1 = pe_b0[col1];
#pragma unroll
    for (int rg = 0; rg < 4; ++rg) {
      int nn = nb0 + q * 4 + rg;
      p1h[(size_t)nn * 128 + col0] = f2h(a2[0][rg] + bb0);
      p1h[(size_t)nn * 128 + col1] = f2h(a2[1][rg] + bb1);
    }
    return;
  }

  // ---- sort role ----
  __shared__ int shT;
  __shared__ int shFlag;
  __shared__ int sbuf[256];
  bool amScan = false;

  for (;;) {                                       // work-steal hist chunks (256 edges)
    if (tid == 0) shT = atomicAdd(&ctr[0], 1);
    __syncthreads();
    int ht = shT;
    __syncthreads();
    if (ht >= 2500) break;
    int e = ht * 256 + tid;
    atomicAdd(&hist[rcv[e]], 1);
    __threadfence();
    __syncthreads();
    if (tid == 0) {
      int d = atomicAdd(&ctr[1], 1);
      shFlag = (d == 2499) ? 1 : 0;
    }
    __syncthreads();
    if (shFlag) amScan = true;                     // block-uniform
  }

  if (amScan) {                                    // one block scans 20000 bins
    int lo = tid * 79;
    int s = 0;
    for (int j = 0; j < 79; ++j) {
      int i = lo + j;
      if (i < N_NODES) s += hist[i];
    }
    sbuf[tid] = s;
    __syncthreads();
    for (int off = 1; off < 256; off <<= 1) {
      int t = (tid >= off) ? sbuf[tid - off] : 0;
      __syncthreads();
      sbuf[tid] += t;
      __syncthreads();
    }
    int run = sbuf[tid] - s;                       // exclusive prefix of chunk
    for (int j = 0; j < 79; ++j) {
      int i = lo + j;
      if (i < N_NODES) { cursor[i] = run; run += hist[i]; }
    }
    __threadfence();
    __syncthreads();
    if (tid == 0) atomicExch(&ctr[2], 1);
  }

  if (tid == 0) {                                  // wait for scan (set by resident block)
    while (atomicAdd(&ctr[2], 0) == 0) __builtin_amdgcn_s_sleep(8);
  }
  __syncthreads();
  __threadfence();

  for (;;) {                                       // work-steal scatter chunks (256 edges)
    if (tid == 0) shT = atomicAdd(&ctr[3], 1);
    __syncthreads();
    int st = shT;
    __syncthreads();
    if (st >= 2500) break;
    int e = st * 256 + tid;
    int r = rcv[e];
    int p = atomicAdd(&cursor[r], 1);
    sedge[p] = (uint)snd[e] | ((uint)r << 16);     // both < 65536
  }
}

// ---------------- fused edge kernel + ticket-gated node epilogue ----------------
__global__ __launch_bounds__(256, 7) void edge_node_kernel(
    const float* __restrict__ pos,
    const ushort* __restrict__ p0h, const ushort* __restrict__ p1h,
    const uint* __restrict__ sedge,
    const ushort* __restrict__ wq, const ushort* __restrict__ ewq,
    const float* __restrict__ pe_w0,
    const float* __restrict__ pe_b1,
    const float* __restrict__ px_b0, const float* __restrict__ px_b1,
    const float* __restrict__ px_out_b, const float* __restrict__ e_b,
    float* __restrict__ outv, ushort* macc16,
    const ushort* __restrict__ featb,
    const float* __restrict__ ph_b0, const float* __restrict__ ph_b1,
    const float* __restrict__ ph_b2,
    float* __restrict__ outf, int* ctr) {
  __shared__ ushort XA[64 * XS];          // 17408 B
  __shared__ float sacc[64][4];
  __shared__ float lenf[64], pp[64], egl[64];
  __shared__ float vec3[64][3];
  __shared__ int segid[64];
  __shared__ int segrcv[64];
  __shared__ int nsegS;
  __shared__ int tkS;

  const int tid = threadIdx.x;
  const int base = blockIdx.x * 64;
  const int lane = tid & 63;
  const int wv = tid >> 6;
  const int c = lane & 15, q = lane >> 4;
  const int n0 = wv * 32;
  const int col0 = n0 + c, col1 = col0 + 16;

  ((float*)sacc)[tid] = 0.0f;

  if (tid < 64) {
    int r = (int)(sedge[base + tid] >> 16);
    int prev = (tid == 0) ? -1 : (int)(sedge[base + tid - 1] >> 16);
    bool bnd = (r != prev);
    unsigned long long bm = __ballot(bnd);
    int sid = (int)__popcll(bm << (63 - tid)) - 1;
    segid[tid] = sid;
    if (bnd) segrcv[sid] = r;
    if (tid == 0) nsegS = (int)__popcll(bm);
  }

  // ---- stage h0 = silu(P0[s] + P1'[r] + L*wL) ----
  {
    int row = tid >> 2, sub = tid & 3;
    uint v = sedge[base + row];
    int s = (int)(v & 0xffffu), r = (int)(v >> 16);
    float vx = pos[r * 3 + 0] - pos[s * 3 + 0];
    float vy = pos[r * 3 + 1] - pos[s * 3 + 1];
    float vz = pos[r * 3 + 2] - pos[s * 3 + 2];
    float n2 = vx * vx + vy * vy + vz * vz;
    float L = (n2 > 0.0f) ? sqrtf(n2) : 0.0f;
    if (sub == 0) {
      vec3[row][0] = vx; vec3[row][1] = vy; vec3[row][2] = vz;
      lenf[row] = L;
    }
    const int cb = sub * 32;
    const uint* a0 = (const uint*)(p0h + (size_t)s * 128) + sub * 16;
    const uint* a1 = (const uint*)(p1h + (size_t)r * 128) + sub * 16;
    const float* wL = pe_w0 + 256 * 128 + cb;
    uint* d = (uint*)(XA + row * XS + cb);
#pragma unroll
    for (int j = 0; j < 16; ++j) {
      uint u0 = a0[j], u1 = a1[j];
      float x = lo16f(u0) + lo16f(u1) + L * wL[2 * j];
      float y = hi16f(u0) + hi16f(u1) + L * wL[2 * j + 1];
      d[j] = cvt_pk_bf16(silu(x), silu(y));
    }
  }
  BAR();   // BAR1

  const int nseg = nsegS;
  const f32x4 z4 = {0.f, 0.f, 0.f, 0.f};

  // ---- phi_e layer 1 ----
  f32x4 accm[4][2];
#pragma unroll
  for (int mt = 0; mt < 4; ++mt) { accm[mt][0] = z4; accm[mt][1] = z4; }
  gemm2(XA, wq + 2 * 16384 + n0 * 128, c, q, accm);
  {
    float b0 = pe_b1[col0], b1 = pe_b1[col1];
#pragma unroll
    for (int mt = 0; mt < 4; ++mt)
#pragma unroll
      for (int rg = 0; rg < 4; ++rg) {
        accm[mt][0][rg] = silu(accm[mt][0][rg] + b0);
        accm[mt][1][rg] = silu(accm[mt][1][rg] + b1);
      }
  }
  BAR();   // BAR2
  {
#pragma unroll
    for (int mt = 0; mt < 4; ++mt)
#pragma unroll
      for (int rg = 0; rg < 4; ++rg) {
        int row = mt * 16 + q * 4 + rg;
        uint u = cvt_pk_bf16(accm[mt][0][rg], accm[mt][1][rg]);
        XA[row * XS + col0] = (ushort)u;
        XA[row * XS + col1] = (ushort)(u >> 16);
      }
  }
  BAR();   // BAR3: m visible

  // ---- gate via distributed MFMA dot ----
  {
    f32x4 accg = z4;
    gemm_dot16(XA + (wv * 16) * XS, ewq, c, q, &accg);
    if (c == 0) {
      float eb = e_b[0];
#pragma unroll
      for (int rg = 0; rg < 4; ++rg)
        egl[wv * 16 + q * 4 + rg] = sigmoid_fast(accg[rg] + eb);
    }
  }
  // ---- phi_x layer 0 ----
  f32x4 accx[4][2];
#pragma unroll
  for (int mt = 0; mt < 4; ++mt) { accx[mt][0] = z4; accx[mt][1] = z4; }
  gemm2(XA, wq + 3 * 16384 + n0 * 128, c, q, accx);
  BAR();   // BAR4: egl visible; all waves done with XA(m)

  // ---- gated m_i: register segmented reduce + ~nseg*32 pk-f16 atomics ----
  {
    float em[4][2][4];
    int sid_[4][4];
#pragma unroll
    for (int mt = 0; mt < 4; ++mt)
#pragma unroll
      for (int rg = 0; rg < 4; ++rg) {
        int row = mt * 16 + q * 4 + rg;
        float eg = egl[row];
        sid_[mt][rg] = segid[row];
        em[mt][0][rg] = accm[mt][0][rg] * eg;
        em[mt][1][rg] = accm[mt][1][rg] * eg;
      }
    for (int sg = 0; sg < nseg; ++sg) {
      float t0 = 0.0f, t1 = 0.0f;
#pragma unroll
      for (int mt = 0; mt < 4; ++mt)
#pragma unroll
        for (int rg = 0; rg < 4; ++rg) {
          bool in = (sid_[mt][rg] == sg);
          t0 += in ? em[mt][0][rg] : 0.0f;
          t1 += in ? em[mt][1][rg] : 0.0f;
        }
      t0 += __shfl_xor(t0, 16); t0 += __shfl_xor(t0, 32);
      t1 += __shfl_xor(t1, 16); t1 += __shfl_xor(t1, 32);
      float o0 = __shfl_xor(t0, 1), o1 = __shfl_xor(t1, 1);
      if (q == 0 && !(c & 1)) {
        ushort* dst = macc16 + (size_t)segrcv[sg] * 128;
        pk_atomic_f16(dst + n0 + c, t0, o0);
        pk_atomic_f16(dst + n0 + 16 + c, t1, o1);
      }
    }
  }
  // ---- px0 -> XA ----
  {
    float b0 = px_b0[col0], b1 = px_b0[col1];
#pragma unroll
    for (int mt = 0; mt < 4; ++mt)
#pragma unroll
      for (int rg = 0; rg < 4; ++rg) {
        int row = mt * 16 + q * 4 + rg;
        uint u = cvt_pk_bf16(silu(accx[mt][0][rg] + b0),
                             silu(accx[mt][1][rg] + b1));
        XA[row * XS + col0] = (ushort)u;
        XA[row * XS + col1] = (ushort)(u >> 16);
      }
  }
  BAR();   // BAR5

  // ---- phi_x layer 1 ----
  f32x4 accy[4][2];
#pragma unroll
  for (int mt = 0; mt < 4; ++mt) { accy[mt][0] = z4; accy[mt][1] = z4; }
  gemm2(XA, wq + 4 * 16384 + n0 * 128, c, q, accy);
  BAR();   // BAR6
  {
    float b0 = px_b1[col0], b1 = px_b1[col1];
#pragma unroll
    for (int mt = 0; mt < 4; ++mt)
#pragma unroll
      for (int rg = 0; rg < 4; ++rg) {
        int row = mt * 16 + q * 4 + rg;
        uint u = cvt_pk_bf16(silu(accy[mt][0][rg] + b0),
                             silu(accy[mt][1][rg] + b1));
        XA[row * XS + col0] = (ushort)u;
        XA[row * XS + col1] = (ushort)(u >> 16);
      }
  }
  BAR();   // BAR7

  // ---- phi_x tail via distributed MFMA dot ----
  {
    f32x4 accp = z4;
    gemm_dot16(XA + (wv * 16) * XS, ewq + 2048, c, q, &accp);
    if (c == 0) {
#pragma unroll
      for (int rg = 0; rg < 4; ++rg)
        pp[wv * 16 + q * 4 + rg] = accp[rg];
    }
  }
  BAR();   // BAR8

  if (tid < 192) {
    int ee = tid / 3, cc = tid - ee * 3;
    float phi = pp[ee] + px_out_b[0];
    float sh = phi * vec3[ee][cc] * __builtin_amdgcn_rcpf(1.0f + lenf[ee]);
    atomicAdd(&sacc[segid[ee]][cc], sh);
  }
  BAR();   // BAR9
  if (tid < nseg * 3) {
    int sg = tid / 3, cc = tid - sg * 3;
    atomicAdd(&outv[(size_t)segrcv[sg] * 3 + cc], sacc[sg][cc]);
  }

  // ================= ticket-gated node epilogue =================
  __threadfence();                                 // release: all atomics visible
  if (tid == 0) tkS = atomicAdd(&ctr[4], 1);
  __syncthreads();
  const int tk = tkS;
  if (tk < TKTH) return;                           // early finishers retire

  if (tid == 0) {                                  // wait for ALL edge blocks
    while (atomicAdd(&ctr[4], 0) < NEBLK) __builtin_amdgcn_s_sleep(8);
  }
  __syncthreads();
  __threadfence();                                 // acquire

  const int nb0 = (tk - TKTH) * 16;
  // stage m_i (coherent atomic reads) into XA rows 0-15; feat into rows 16-31
  {
    int row = tid >> 4, sub = tid & 15;
    int nn = nb0 + row;
    const ushort* mp = macc16 + (size_t)nn * 128 + sub * 8;
    uint* d = (uint*)(XA + row * XS) + sub * 4;
#pragma unroll
    for (int j = 0; j < 4; ++j) {
      f16x2 v = pk_atomic_read16(mp + 2 * j);
      d[j] = cvt_pk_bf16((float)v.x * INV_SQRT_AVG, (float)v.y * INV_SQRT_AVG);
    }
    const bf16x8* s = (const bf16x8*)(featb + (size_t)nn * 128);
    ((bf16x8*)(XA + (16 + row) * XS))[sub] = s[sub];
  }
  BAR();

  f32x4 a2[2];
  a2[0] = z4; a2[1] = z4;
  // ---- ph layer 0: [m_i | feat] ----
  gemm1(XA, wq + 5 * 16384 + n0 * 128, c, q, a2);
  gemm1(XA + 16 * XS, wq + 6 * 16384 + n0 * 128, c, q, a2);
  BAR();
  {
    float b0 = ph_b0[col0], b1 = ph_b0[col1];
#pragma unroll
    for (int rg = 0; rg < 4; ++rg) {
      int row = q * 4 + rg;
      uint u = cvt_pk_bf16(silu(a2[0][rg] + b0), silu(a2[1][rg] + b1));
      XA[row * XS + col0] = (ushort)u;
      XA[row * XS + col1] = (ushort)(u >> 16);
    }
  }
  BAR();

  // ---- ph layer 1 ----
  a2[0] = z4; a2[1] = z4;
  gemm1(XA, wq + 7 * 16384 + n0 * 128, c, q, a2);
  BAR();
  {
    float b0 = ph_b1[col0], b1 = ph_b1[col1];
#pragma unroll
    for (int rg = 0; rg < 4; ++rg) {
      int row = q * 4 + rg;
      uint u = cvt_pk_bf16(silu(a2[0][rg] + b0), silu(a2[1][rg] + b1));
      XA[row * XS + col0] = (ushort)u;
      XA[row * XS + col1] = (ushort)(u >> 16);
    }
  }
  BAR();

  // ---- ph layer 2 (no act) + residual from XA rows 16-31 ----
  a2[0] = z4; a2[1] = z4;
  gemm1(XA, wq + 8 * 16384 + n0 * 128, c, q, a2);
  {
    float b0 = ph_b2[col0], b1 = ph_b2[col1];
#pragma unroll
    for (int rg = 0; rg < 4; ++rg) {
      int row = q * 4 + rg;
      size_t o = (size_t)(nb0 + row) * 128;
      float r0 = b2f(XA[(16 + row) * XS + col0]);
      float r1 = b2f(XA[(16 + row) * XS + col1]);
      outf[o + col0] = a2[0][rg] + b0 + r0;
      outf[o + col1] = a2[1][rg] + b1 + r1;
    }
  }
  if (tid < 48) {
    int nl = tid / 3, cc = tid - nl * 3;
    int nn = nb0 + nl;
    float ov = atomicAdd(&outv[nn * 3 + cc], 0.0f);   // coherent read
    outv[nn * 3 + cc] = pos[nn * 3 + cc] + ov * INV_AVG;
  }
}

// ---------------- launch ----------------
extern "C" void kernel_launch(void* const* d_in, const int* in_sizes, int n_in,
                              void* d_out, int out_size, void* d_ws, size_t ws_size,
                              hipStream_t stream) {
  const float* pos  = (const float*)d_in[0];
  const float* feat = (const float*)d_in[1];
  const float* pe_w0 = (const float*)d_in[2];
  const float* pe_b0 = (const float*)d_in[3];
  const float* pe_b1 = (const float*)d_in[5];
  const float* px_b0 = (const float*)d_in[7];
  const float* px_b1 = (const float*)d_in[9];
  const float* px_out_w = (const float*)d_in[10];
  const float* px_out_b = (const float*)d_in[11];
  const float* e_w = (const float*)d_in[12];
  const float* e_b = (const float*)d_in[13];
  const float* ph_b0 = (const float*)d_in[15];
  const float* ph_b1 = (const float*)d_in[17];
  const float* ph_b2 = (const float*)d_in[19];
  const int* snd = (const int*)d_in[20];
  const int* rcv = (const int*)d_in[21];

  // d_ws: wq + featb (5.41 MB proven) + 32 B of sync counters
  ushort* wq = (ushort*)d_ws;
  ushort* featb = wq + FEATB_OFF;
  int* ctr = (int*)(featb + N_NODES * 128);        // byte 5,414,912 (4B aligned)

  // d_in[1]: [0,5.12MB) f16 m_acc; [5.12,10.24) P0 (f16)
  ushort* macc16 = (ushort*)d_in[1];
  ushort* p0h    = macc16 + 2560000;

  float* out  = (float*)d_out;
  float* outf = out + 60000;
  // outf scratch (dead before node output overwrites it):
  //   sedge 2.56MB | p1h 5.12MB | hist 80KB | cursor 80KB | ewq 8KB = 7.85MB
  uint*   sedge  = (uint*)outf;
  ushort* p1h    = (ushort*)(sedge + N_EDGES);
  int*    hist   = (int*)(p1h + 2560000);
  int*    cursor = hist + N_NODES;
  ushort* ewq    = (ushort*)(cursor + N_NODES);

  PrepArgs a;
  a.src[0] = pe_w0;
  a.src[1] = pe_w0 + 128 * 128;
  a.src[2] = (const float*)d_in[4];               // pe_w1
  a.src[3] = (const float*)d_in[6];               // px_w0
  a.src[4] = (const float*)d_in[8];               // px_w1
  a.src[5] = (const float*)d_in[14];              // ph_w0 (m_i half)
  a.src[6] = (const float*)d_in[14] + 128 * 128;  // ph_w0 (feat half)
  a.src[7] = (const float*)d_in[16];              // ph_w1
  a.src[8] = (const float*)d_in[18];              // ph_w2

  setup_kernel<<<(N_NODES * 128) / 256, 256, 0, stream>>>(
      a, feat, wq, featb, (uint*)macc16, hist, ctr, ewq, e_w, px_out_w);

  megaprep_kernel<<<6250, 256, 0, stream>>>(
      snd, rcv, hist, cursor, sedge, ctr, featb, wq, pe_b0, p0h, p1h, out);

  edge_node_kernel<<<NEBLK, 256, 0, stream>>>(
      pos, p0h, p1h, sedge, wq, ewq,
      pe_w0, pe_b1, px_b0, px_b1, px_out_b, e_b,
      out, macc16, featb, ph_b0, ph_b1, ph_b2, outf, ctr);
}

// Round 10
// 567.917 us; speedup vs baseline: 5.2329x; 5.2329x over previous
//
#include <hip/hip_runtime.h>

#define N_NODES 20000
#define N_EDGES 640000
#define XS 136   // LDS activation row stride in bf16 units (128 + 8 pad)

#define INV_SQRT_AVG 0.0070714082f   // 1/sqrt(19999)
#define INV_AVG      5.000250e-5f    // 1/19999

#define FEATB_OFF 147456             // ushort offset of bf16 feat table in ws (after 9*16384 weights)

typedef __attribute__((ext_vector_type(8))) short bf16x8;
typedef __attribute__((ext_vector_type(4))) float f32x4;
typedef __attribute__((ext_vector_type(2))) _Float16 f16x2;

// Non-draining barrier: LDS ordering only (proven neutral-correct earlier).
#define BAR() asm volatile("s_waitcnt lgkmcnt(0)\n\ts_barrier" ::: "memory")

__device__ __forceinline__ ushort f2b(float f) {
  unsigned x = __float_as_uint(f);
  unsigned r = (x + 0x7fffu + ((x >> 16) & 1u)) >> 16;   // RNE
  return (ushort)r;
}
__device__ __forceinline__ uint cvt_pk_bf16(float lo, float hi) {
  uint r;
  asm("v_cvt_pk_bf16_f32 %0, %1, %2" : "=v"(r) : "v"(lo), "v"(hi));
  return r;
}
__device__ __forceinline__ float silu(float v) {
  return v * __builtin_amdgcn_rcpf(1.0f + __expf(-v));
}
__device__ __forceinline__ float sigmoid_fast(float v) {
  return __builtin_amdgcn_rcpf(1.0f + __expf(-v));
}
__device__ __forceinline__ float b2f(ushort u) {
  return __uint_as_float(((uint)u) << 16);
}
__device__ __forceinline__ float lo16f(uint u) {
  ushort us = (ushort)(u & 0xffffu);
  _Float16 h; __builtin_memcpy(&h, &us, 2);
  return (float)h;
}
__device__ __forceinline__ float hi16f(uint u) {
  ushort us = (ushort)(u >> 16);
  _Float16 h; __builtin_memcpy(&h, &us, 2);
  return (float)h;
}
__device__ __forceinline__ ushort f2h(float x) {
  _Float16 h = (_Float16)x;
  ushort u; __builtin_memcpy(&u, &h, 2);
  return u;
}
// native packed f16 atomic add (global_atomic_pk_add_f16, gfx90a+)
__device__ __forceinline__ void pk_atomic_f16(ushort* p, float x, float y) {
  typedef __attribute__((address_space(1))) f16x2 gf2;
  f16x2 v = {(_Float16)x, (_Float16)y};
  __builtin_amdgcn_global_atomic_fadd_v2f16((gf2*)(unsigned long long)p, v);
}

// ---------------- setup: weights cvt; feat->bf16; zero f16 m_acc (aliases feat);
// hist atomics (hist pre-zeroed by hipMemsetAsync); ewq tables ----
struct PrepArgs { const float* src[9]; };

__global__ __launch_bounds__(256) void setup_kernel(PrepArgs a,
                                                    const float* feat,
                                                    const int* __restrict__ rcv,
                                                    ushort* __restrict__ wq,
                                                    ushort* __restrict__ featb,
                                                    uint* m_acc32,
                                                    int* __restrict__ hist,
                                                    ushort* __restrict__ ewq,
                                                    const float* __restrict__ e_w,
                                                    const float* __restrict__ px_out_w) {
  int i = blockIdx.x * 256 + threadIdx.x;          // i < 2,560,000 exactly
  float fv = feat[i];
  asm volatile("" ::: "memory");                   // feat read precedes m_acc zero
  featb[i] = f2b(fv);
  if (i < N_NODES * 64) m_acc32[i] = 0u;           // zero f16 m_acc (first 5.12 MB)
  if (i < N_EDGES) atomicAdd(&hist[rcv[i]], 1);    // hist zeroed by prior memset
  if (i < 9 * 16384) {
    int m = i >> 14, idx = i & 16383;
    int k = idx >> 7, n = idx & 127;
    wq[m * 16384 + n * 128 + k] = f2b(a.src[m][k * 128 + n]);
  }
  if (i < 4096) {                                  // ew table [0,2048), pw table [2048,4096)
    int t = i >> 11, idx = i & 2047, col = idx >> 7, k = idx & 127;
    float v = (col == 0) ? (t ? px_out_w[k] : e_w[k]) : 0.0f;
    ewq[i] = f2b(v);
  }
}

// ---------------- MFMA helpers ----------------
// 64 rows x 32 cols per wave; PAIRED columns: lane (c,q) owns cols n0+2c, n0+2c+1
__device__ __forceinline__ void gemm2(const ushort* X, const ushort* __restrict__ Wn0,
                                      int c, int q, f32x4 acc[4][2]) {
  const int kq = q * 8;
  bf16x8 b[2][4];
#pragma unroll
  for (int ct = 0; ct < 2; ++ct)
#pragma unroll
    for (int ks = 0; ks < 4; ++ks)
      b[ct][ks] = *(const bf16x8*)(Wn0 + (2 * c + ct) * 128 + ks * 32 + kq);
#pragma unroll
  for (int mt = 0; mt < 4; ++mt)
#pragma unroll
    for (int ks = 0; ks < 4; ++ks) {
      bf16x8 a = *(const bf16x8*)(X + (mt * 16 + c) * XS + ks * 32 + kq);
      acc[mt][0] = __builtin_amdgcn_mfma_f32_16x16x32_bf16(a, b[0][ks], acc[mt][0], 0, 0, 0);
      acc[mt][1] = __builtin_amdgcn_mfma_f32_16x16x32_bf16(a, b[1][ks], acc[mt][1], 0, 0, 0);
    }
}

// 16 rows x 32 cols per wave (classic c / c+16 mapping — used by precompute & node)
__device__ __forceinline__ void gemm1(const ushort* X, const ushort* __restrict__ Wn0,
                                      int c, int q, f32x4 acc[2]) {
  const int kq = q * 8;
#pragma unroll
  for (int ks = 0; ks < 4; ++ks) {
    bf16x8 a  = *(const bf16x8*)(X + c * XS + ks * 32 + kq);
    bf16x8 b0 = *(const bf16x8*)(Wn0 + c * 128 + ks * 32 + kq);
    bf16x8 b1 = *(const bf16x8*)(Wn0 + (16 + c) * 128 + ks * 32 + kq);
    acc[0] = __builtin_amdgcn_mfma_f32_16x16x32_bf16(a, b0, acc[0], 0, 0, 0);
    acc[1] = __builtin_amdgcn_mfma_f32_16x16x32_bf16(a, b1, acc[1], 0, 0, 0);
  }
}

// per-wave 16-row x 1-col dot (table col0 only nonzero; result on c==0 lanes)
__device__ __forceinline__ void gemm_dot16(const ushort* X, const ushort* __restrict__ T,
                                           int c, int q, f32x4* accd) {
  const int kq = q * 8;
#pragma unroll
  for (int ks = 0; ks < 4; ++ks) {
    bf16x8 bg = *(const bf16x8*)(T + c * 128 + ks * 32 + kq);
    bf16x8 a = *(const bf16x8*)(X + c * XS + ks * 32 + kq);
    *accd = __builtin_amdgcn_mfma_f32_16x16x32_bf16(a, bg, *accd, 0, 0, 0);
  }
}

__device__ __forceinline__ void stage_row16(ushort* X, const ushort* __restrict__ src,
                                            int row, int sub) {
  const bf16x8* s = (const bf16x8*)src;
  ((bf16x8*)(X + row * XS))[sub] = s[sub];
}

// ---------------- scan (block 0) || precompute P0/P1' + zero outv (blocks 1..1250) ----
__global__ __launch_bounds__(256, 4) void scanpre_kernel(
    const int* __restrict__ hist, int* __restrict__ cursor,
    const ushort* __restrict__ featb, const ushort* __restrict__ wq,
    const float* __restrict__ pe_b0,
    ushort* __restrict__ p0h, ushort* __restrict__ p1h,
    float* __restrict__ outv) {
  const int tid = threadIdx.x;

  if (blockIdx.x == 0) {                           // ---- scan role: 20000 bins ----
    __shared__ int sbuf[256];
    const int lo = tid * 79;                       // 256*79 = 20224 >= 20000
    int s = 0;
    for (int j = 0; j < 79; ++j) {
      int i = lo + j;
      if (i < N_NODES) s += hist[i];
    }
    sbuf[tid] = s;
    __syncthreads();
    for (int off = 1; off < 256; off <<= 1) {
      int t = (tid >= off) ? sbuf[tid - off] : 0;
      __syncthreads();
      sbuf[tid] += t;
      __syncthreads();
    }
    int run = sbuf[tid] - s;                       // exclusive prefix of this chunk
    for (int j = 0; j < 79; ++j) {
      int i = lo + j;
      if (i < N_NODES) { cursor[i] = run; run += hist[i]; }
    }
    return;
  }

  // ---- precompute role: 16 nodes/block ----
  __shared__ ushort XA[16 * XS];
  const int pblk = blockIdx.x - 1;
  const int nb0 = pblk * 16;
  const int lane = tid & 63;
  const int wv = tid >> 6;
  const int c = lane & 15, q = lane >> 4;
  const int n0 = wv * 32;
  const int col0 = n0 + c, col1 = col0 + 16;

  int gid = pblk * 256 + tid;                      // 1250*256 = 320000 >= 60000
  if (gid < 60000) outv[gid] = 0.0f;

  {
    int row = tid >> 4, sub = tid & 15;
    stage_row16(XA, featb + (size_t)(nb0 + row) * 128, row, sub);
  }
  BAR();

  const f32x4 z4 = {0.f, 0.f, 0.f, 0.f};
  f32x4 a2[2];
  a2[0] = z4; a2[1] = z4;
  gemm1(XA, wq + 0 * 16384 + n0 * 128, c, q, a2);
#pragma unroll
  for (int rg = 0; rg < 4; ++rg) {
    int nn = nb0 + q * 4 + rg;
    p0h[(size_t)nn * 128 + col0] = f2h(a2[0][rg]);
    p0h[(size_t)nn * 128 + col1] = f2h(a2[1][rg]);
  }
  a2[0] = z4; a2[1] = z4;
  gemm1(XA, wq + 1 * 16384 + n0 * 128, c, q, a2);
  float bb0 = pe_b0[col0], bb1 = pe_b0[col1];      // fold pe_b0 into P1'
#pragma unroll
  for (int rg = 0; rg < 4; ++rg) {
    int nn = nb0 + q * 4 + rg;
    p1h[(size_t)nn * 128 + col0] = f2h(a2[0][rg] + bb0);
    p1h[(size_t)nn * 128 + col1] = f2h(a2[1][rg] + bb1);
  }
}

__global__ __launch_bounds__(256) void scatter_kernel(const int* __restrict__ snd,
                                                      const int* __restrict__ rcv,
                                                      int* __restrict__ cursor,
                                                      uint* __restrict__ sedge) {
  int e = blockIdx.x * 256 + threadIdx.x;          // exact: 2500*256 = 640000
  int r = rcv[e];
  int p = atomicAdd(&cursor[r], 1);
  sedge[p] = (uint)snd[e] | ((uint)r << 16);       // both < 65536
}

// ---------------- edge kernel: sorted edges, 3 GEMMs + 2 distributed MFMA dots,
// paired-column fragments (4B LDS writes, shuffle-free atomic pairs) ----
__global__ __launch_bounds__(256, 7) void edge_kernel(
    const float* __restrict__ pos,
    const ushort* __restrict__ p0h, const ushort* __restrict__ p1h,
    const uint* __restrict__ sedge,
    const ushort* __restrict__ wq, const ushort* __restrict__ ewq,
    const float* __restrict__ pe_w0,
    const float* __restrict__ pe_b1,
    const float* __restrict__ px_b0, const float* __restrict__ px_b1,
    const float* __restrict__ px_out_b, const float* __restrict__ e_b,
    float* __restrict__ outv, ushort* __restrict__ macc16) {
  __shared__ ushort XA[64 * XS];          // 17408 B
  __shared__ float sacc[64][4];
  __shared__ float lenf[64], pp[64], egl[64];
  __shared__ float vec3[64][3];
  __shared__ int segid[64];
  __shared__ int segrcv[64];
  __shared__ int nsegS;

  const int tid = threadIdx.x;
  const int base = blockIdx.x * 64;
  const int lane = tid & 63;
  const int wv = tid >> 6;
  const int c = lane & 15, q = lane >> 4;
  const int n0 = wv * 32;
  const int col0 = n0 + 2 * c, col1 = col0 + 1;   // paired columns

  ((float*)sacc)[tid] = 0.0f;

  if (tid < 64) {
    int r = (int)(sedge[base + tid] >> 16);
    int prev = (tid == 0) ? -1 : (int)(sedge[base + tid - 1] >> 16);
    bool bnd = (r != prev);
    unsigned long long bm = __ballot(bnd);
    int sid = (int)__popcll(bm << (63 - tid)) - 1;
    segid[tid] = sid;
    if (bnd) segrcv[sid] = r;
    if (tid == 0) nsegS = (int)__popcll(bm);
  }

  // ---- stage h0 = silu(P0[s] + P1'[r] + L*wL) ----
  {
    int row = tid >> 2, sub = tid & 3;
    uint v = sedge[base + row];
    int s = (int)(v & 0xffffu), r = (int)(v >> 16);
    float vx = pos[r * 3 + 0] - pos[s * 3 + 0];
    float vy = pos[r * 3 + 1] - pos[s * 3 + 1];
    float vz = pos[r * 3 + 2] - pos[s * 3 + 2];
    float n2 = vx * vx + vy * vy + vz * vz;
    float L = (n2 > 0.0f) ? sqrtf(n2) : 0.0f;
    if (sub == 0) {
      vec3[row][0] = vx; vec3[row][1] = vy; vec3[row][2] = vz;
      lenf[row] = L;
    }
    const int cb = sub * 32;
    const uint* a0 = (const uint*)(p0h + (size_t)s * 128) + sub * 16;
    const uint* a1 = (const uint*)(p1h + (size_t)r * 128) + sub * 16;
    const float* wL = pe_w0 + 256 * 128 + cb;
    uint* d = (uint*)(XA + row * XS + cb);
#pragma unroll
    for (int j = 0; j < 16; ++j) {
      uint u0 = a0[j], u1 = a1[j];
      float x = lo16f(u0) + lo16f(u1) + L * wL[2 * j];
      float y = hi16f(u0) + hi16f(u1) + L * wL[2 * j + 1];
      d[j] = cvt_pk_bf16(silu(x), silu(y));
    }
  }
  BAR();   // BAR1

  const int nseg = nsegS;
  const f32x4 z4 = {0.f, 0.f, 0.f, 0.f};

  // ---- phi_e layer 1: XA(h0) -> m ----
  f32x4 accm[4][2];
#pragma unroll
  for (int mt = 0; mt < 4; ++mt) { accm[mt][0] = z4; accm[mt][1] = z4; }
  gemm2(XA, wq + 2 * 16384 + n0 * 128, c, q, accm);
  {
    float b0 = pe_b1[col0], b1 = pe_b1[col1];
#pragma unroll
    for (int mt = 0; mt < 4; ++mt)
#pragma unroll
      for (int rg = 0; rg < 4; ++rg) {
        accm[mt][0][rg] = silu(accm[mt][0][rg] + b0);
        accm[mt][1][rg] = silu(accm[mt][1][rg] + b1);
      }
  }
  BAR();   // BAR2: all waves done reading h0
  {
#pragma unroll
    for (int mt = 0; mt < 4; ++mt)
#pragma unroll
      for (int rg = 0; rg < 4; ++rg) {
        int row = mt * 16 + q * 4 + rg;
        *(uint*)(XA + row * XS + col0) = cvt_pk_bf16(accm[mt][0][rg], accm[mt][1][rg]);
      }
  }
  BAR();   // BAR3: m visible

  // ---- gate via distributed MFMA dot ----
  {
    f32x4 accg = z4;
    gemm_dot16(XA + (wv * 16) * XS, ewq, c, q, &accg);
    if (c == 0) {
      float eb = e_b[0];
#pragma unroll
      for (int rg = 0; rg < 4; ++rg)
        egl[wv * 16 + q * 4 + rg] = sigmoid_fast(accg[rg] + eb);
    }
  }
  // ---- phi_x layer 0 ----
  f32x4 accx[4][2];
#pragma unroll
  for (int mt = 0; mt < 4; ++mt) { accx[mt][0] = z4; accx[mt][1] = z4; }
  gemm2(XA, wq + 3 * 16384 + n0 * 128, c, q, accx);
  BAR();   // BAR4: egl visible; all waves done with XA(m)

  // ---- gated m_i: register segmented reduce; pair (col0,col1) -> ONE pk atomic ----
  {
    float em[4][2][4];
    int sid_[4][4];
#pragma unroll
    for (int mt = 0; mt < 4; ++mt)
#pragma unroll
      for (int rg = 0; rg < 4; ++rg) {
        int row = mt * 16 + q * 4 + rg;
        float eg = egl[row];
        sid_[mt][rg] = segid[row];
        em[mt][0][rg] = accm[mt][0][rg] * eg;
        em[mt][1][rg] = accm[mt][1][rg] * eg;
      }
    for (int sg = 0; sg < nseg; ++sg) {
      float t0 = 0.0f, t1 = 0.0f;
#pragma unroll
      for (int mt = 0; mt < 4; ++mt)
#pragma unroll
        for (int rg = 0; rg < 4; ++rg) {
          bool in = (sid_[mt][rg] == sg);
          t0 += in ? em[mt][0][rg] : 0.0f;
          t1 += in ? em[mt][1][rg] : 0.0f;
        }
      t0 += __shfl_xor(t0, 16); t0 += __shfl_xor(t0, 32);
      t1 += __shfl_xor(t1, 16); t1 += __shfl_xor(t1, 32);
      if (q == 0) {
        ushort* dst = macc16 + (size_t)segrcv[sg] * 128;
        pk_atomic_f16(dst + col0, t0, t1);         // adjacent cols: one atomic
      }
    }
  }
  // ---- px0 -> XA ----
  {
    float b0 = px_b0[col0], b1 = px_b0[col1];
#pragma unroll
    for (int mt = 0; mt < 4; ++mt)
#pragma unroll
      for (int rg = 0; rg < 4; ++rg) {
        int row = mt * 16 + q * 4 + rg;
        *(uint*)(XA + row * XS + col0) = cvt_pk_bf16(silu(accx[mt][0][rg] + b0),
                                                     silu(accx[mt][1][rg] + b1));
      }
  }
  BAR();   // BAR5

  // ---- phi_x layer 1 ----
  f32x4 accy[4][2];
#pragma unroll
  for (int mt = 0; mt < 4; ++mt) { accy[mt][0] = z4; accy[mt][1] = z4; }
  gemm2(XA, wq + 4 * 16384 + n0 * 128, c, q, accy);
  BAR();   // BAR6
  {
    float b0 = px_b1[col0], b1 = px_b1[col1];
#pragma unroll
    for (int mt = 0; mt < 4; ++mt)
#pragma unroll
      for (int rg = 0; rg < 4; ++rg) {
        int row = mt * 16 + q * 4 + rg;
        *(uint*)(XA + row * XS + col0) = cvt_pk_bf16(silu(accy[mt][0][rg] + b0),
                                                     silu(accy[mt][1][rg] + b1));
      }
  }
  BAR();   // BAR7

  // ---- phi_x tail via distributed MFMA dot ----
  {
    f32x4 accp = z4;
    gemm_dot16(XA + (wv * 16) * XS, ewq + 2048, c, q, &accp);
    if (c == 0) {
#pragma unroll
      for (int rg = 0; rg < 4; ++rg)
        pp[wv * 16 + q * 4 + rg] = accp[rg];
    }
  }
  BAR();   // BAR8

  if (tid < 192) {
    int ee = tid / 3, cc = tid - ee * 3;
    float phi = pp[ee] + px_out_b[0];
    float sh = phi * vec3[ee][cc] * __builtin_amdgcn_rcpf(1.0f + lenf[ee]);
    atomicAdd(&sacc[segid[ee]][cc], sh);
  }
  BAR();   // BAR9
  if (tid < nseg * 3) {
    int sg = tid / 3, cc = tid - sg * 3;
    atomicAdd(&outv[(size_t)segrcv[sg] * 3 + cc], sacc[sg][cc]);
  }
}

// ---------------- node kernel: 16-node tiles (1250 blocks), f16 m_acc in ----------------
__global__ __launch_bounds__(256, 5) void node_kernel(
    const float* __restrict__ pos,
    const ushort* __restrict__ featb, const ushort* __restrict__ wq,
    const ushort* __restrict__ outm,
    const float* __restrict__ ph_b0, const float* __restrict__ ph_b1,
    const float* __restrict__ ph_b2,
    float* __restrict__ outv, float* __restrict__ outf) {
  __shared__ ushort XA[16 * XS];
  __shared__ ushort XB[16 * XS];

  const int tid = threadIdx.x;
  const int nb0 = blockIdx.x * 16;      // 1250*16 = 20000 exact
  const int lane = tid & 63;
  const int wv = tid >> 6;
  const int c = lane & 15, q = lane >> 4;
  const int n0 = wv * 32;
  const int col0 = n0 + c, col1 = col0 + 16;

  {
    int row = tid >> 4, sub = tid & 15;   // 16 threads/row
    int nn = nb0 + row;
    const uint* s4 = (const uint*)(outm + (size_t)nn * 128) + sub * 4;
    uint* d = (uint*)(XA + row * XS) + sub * 4;
#pragma unroll
    for (int j = 0; j < 4; ++j) {
      uint u = s4[j];
      d[j] = cvt_pk_bf16(lo16f(u) * INV_SQRT_AVG, hi16f(u) * INV_SQRT_AVG);
    }
    stage_row16(XB, featb + (size_t)nn * 128, row, sub);
  }
  BAR();

  const f32x4 z4 = {0.f, 0.f, 0.f, 0.f};
  f32x4 a2[2];
  a2[0] = z4; a2[1] = z4;

  // ---- ph layer 0: [m_i | feat] ----
  gemm1(XA, wq + 5 * 16384 + n0 * 128, c, q, a2);
  gemm1(XB, wq + 6 * 16384 + n0 * 128, c, q, a2);
  BAR();
  {
    float b0 = ph_b0[col0], b1 = ph_b0[col1];
#pragma unroll
    for (int rg = 0; rg < 4; ++rg) {
      int row = q * 4 + rg;
      uint u = cvt_pk_bf16(silu(a2[0][rg] + b0), silu(a2[1][rg] + b1));
      XA[row * XS + col0] = (ushort)u;
      XA[row * XS + col1] = (ushort)(u >> 16);
    }
  }
  BAR();

  // ---- ph layer 1 ----
  a2[0] = z4; a2[1] = z4;
  gemm1(XA, wq + 7 * 16384 + n0 * 128, c, q, a2);
  BAR();
  {
    float b0 = ph_b1[col0], b1 = ph_b1[col1];
#pragma unroll
    for (int rg = 0; rg < 4; ++rg) {
      int row = q * 4 + rg;
      uint u = cvt_pk_bf16(silu(a2[0][rg] + b0), silu(a2[1][rg] + b1));
      XA[row * XS + col0] = (ushort)u;
      XA[row * XS + col1] = (ushort)(u >> 16);
    }
  }
  BAR();

  // ---- ph layer 2 (no act) + residual from XB(featb) ----
  a2[0] = z4; a2[1] = z4;
  gemm1(XA, wq + 8 * 16384 + n0 * 128, c, q, a2);
  {
    float b0 = ph_b2[col0], b1 = ph_b2[col1];
#pragma unroll
    for (int rg = 0; rg < 4; ++rg) {
      int row = q * 4 + rg;
      size_t o = (size_t)(nb0 + row) * 128;
      float r0 = b2f(XB[row * XS + col0]);
      float r1 = b2f(XB[row * XS + col1]);
      outf[o + col0] = a2[0][rg] + b0 + r0;
      outf[o + col1] = a2[1][rg] + b1 + r1;
    }
  }
  if (tid < 48) {
    int nl = tid / 3, cc = tid - nl * 3;
    int nn = nb0 + nl;
    outv[nn * 3 + cc] = pos[nn * 3 + cc] + outv[nn * 3 + cc] * INV_AVG;
  }
}

// ---------------- launch ----------------
extern "C" void kernel_launch(void* const* d_in, const int* in_sizes, int n_in,
                              void* d_out, int out_size, void* d_ws, size_t ws_size,
                              hipStream_t stream) {
  const float* pos  = (const float*)d_in[0];
  const float* feat = (const float*)d_in[1];
  const float* pe_w0 = (const float*)d_in[2];
  const float* pe_b0 = (const float*)d_in[3];
  const float* pe_b1 = (const float*)d_in[5];
  const float* px_b0 = (const float*)d_in[7];
  const float* px_b1 = (const float*)d_in[9];
  const float* px_out_w = (const float*)d_in[10];
  const float* px_out_b = (const float*)d_in[11];
  const float* e_w = (const float*)d_in[12];
  const float* e_b = (const float*)d_in[13];
  const float* ph_b0 = (const float*)d_in[15];
  const float* ph_b1 = (const float*)d_in[17];
  const float* ph_b2 = (const float*)d_in[19];
  const int* snd = (const int*)d_in[20];
  const int* rcv = (const int*)d_in[21];

  // d_ws: wq + featb (5.41 MB — proven footprint)
  ushort* wq = (ushort*)d_ws;
  ushort* featb = wq + FEATB_OFF;

  // d_in[1]: [0,5.12MB) f16 m_acc; [5.12,10.24) P0 (f16)
  ushort* macc16 = (ushort*)d_in[1];
  ushort* p0h    = macc16 + 2560000;

  float* out  = (float*)d_out;
  float* outf = out + 60000;
  // outf scratch (dead before node output overwrites it):
  //   sedge 2.56MB | p1h 5.12MB | hist 80KB | cursor 80KB | ewq 8KB = 7.85MB
  uint*   sedge  = (uint*)outf;
  ushort* p1h    = (ushort*)(sedge + N_EDGES);
  int*    hist   = (int*)(p1h + 2560000);
  int*    cursor = hist + N_NODES;
  ushort* ewq    = (ushort*)(cursor + N_NODES);

  PrepArgs a;
  a.src[0] = pe_w0;
  a.src[1] = pe_w0 + 128 * 128;
  a.src[2] = (const float*)d_in[4];               // pe_w1
  a.src[3] = (const float*)d_in[6];               // px_w0
  a.src[4] = (const float*)d_in[8];               // px_w1
  a.src[5] = (const float*)d_in[14];              // ph_w0 (m_i half)
  a.src[6] = (const float*)d_in[14] + 128 * 128;  // ph_w0 (feat half)
  a.src[7] = (const float*)d_in[16];              // ph_w1
  a.src[8] = (const float*)d_in[18];              // ph_w2

  hipMemsetAsync(hist, 0, N_NODES * sizeof(int), stream);

  setup_kernel<<<(N_NODES * 128) / 256, 256, 0, stream>>>(
      a, feat, rcv, wq, featb, (uint*)macc16, hist, ewq, e_w, px_out_w);

  // scan (block 0) || precompute P0/P1' + zero outv (blocks 1..1250)
  scanpre_kernel<<<1251, 256, 0, stream>>>(hist, cursor, featb, wq, pe_b0,
                                           p0h, p1h, out);

  scatter_kernel<<<N_EDGES / 256, 256, 0, stream>>>(snd, rcv, cursor, sedge);

  edge_kernel<<<N_EDGES / 64, 256, 0, stream>>>(
      pos, p0h, p1h, sedge, wq, ewq,
      pe_w0, pe_b1, px_b0, px_b1, px_out_b, e_b,
      out, macc16);

  node_kernel<<<N_NODES / 16, 256, 0, stream>>>(
      pos, featb, wq, macc16, ph_b0, ph_b1, ph_b2,
      out, outf);
}

// Round 11
// 483.848 us; speedup vs baseline: 6.1422x; 1.1738x over previous
//
#include <hip/hip_runtime.h>

#define N_NODES 20000
#define N_EDGES 640000
#define XS 136   // LDS activation row stride in bf16 units (128 + 8 pad)

#define INV_SQRT_AVG 0.0070714082f   // 1/sqrt(19999)
#define INV_AVG      5.000250e-5f    // 1/19999

#define FEATB_OFF 147456             // ushort offset of bf16 feat table in ws (after 9*16384 weights)

typedef __attribute__((ext_vector_type(8))) short bf16x8;
typedef __attribute__((ext_vector_type(4))) float f32x4;
typedef __attribute__((ext_vector_type(2))) _Float16 f16x2;

// Non-draining barrier: LDS ordering only (proven neutral-correct earlier).
#define BAR() asm volatile("s_waitcnt lgkmcnt(0)\n\ts_barrier" ::: "memory")

__device__ __forceinline__ ushort f2b(float f) {
  unsigned x = __float_as_uint(f);
  unsigned r = (x + 0x7fffu + ((x >> 16) & 1u)) >> 16;   // RNE
  return (ushort)r;
}
__device__ __forceinline__ uint cvt_pk_bf16(float lo, float hi) {
  uint r;
  asm("v_cvt_pk_bf16_f32 %0, %1, %2" : "=v"(r) : "v"(lo), "v"(hi));
  return r;
}
__device__ __forceinline__ float silu(float v) {
  return v * __builtin_amdgcn_rcpf(1.0f + __expf(-v));
}
__device__ __forceinline__ float sigmoid_fast(float v) {
  return __builtin_amdgcn_rcpf(1.0f + __expf(-v));
}
__device__ __forceinline__ float b2f(ushort u) {
  return __uint_as_float(((uint)u) << 16);
}
__device__ __forceinline__ float lo16f(uint u) {
  ushort us = (ushort)(u & 0xffffu);
  _Float16 h; __builtin_memcpy(&h, &us, 2);
  return (float)h;
}
__device__ __forceinline__ float hi16f(uint u) {
  ushort us = (ushort)(u >> 16);
  _Float16 h; __builtin_memcpy(&h, &us, 2);
  return (float)h;
}
__device__ __forceinline__ ushort f2h(float x) {
  _Float16 h = (_Float16)x;
  ushort u; __builtin_memcpy(&u, &h, 2);
  return u;
}
// native packed f16 atomic add (global_atomic_pk_add_f16, gfx90a+)
__device__ __forceinline__ void pk_atomic_f16(ushort* p, float x, float y) {
  typedef __attribute__((address_space(1))) f16x2 gf2;
  f16x2 v = {(_Float16)x, (_Float16)y};
  __builtin_amdgcn_global_atomic_fadd_v2f16((gf2*)(unsigned long long)p, v);
}

// ---------------- setup: weights cvt; feat->bf16; zero f16 m_acc (aliases feat);
// hist atomics (hist pre-zeroed by hipMemsetAsync); ewq tables ----
struct PrepArgs { const float* src[9]; };

__global__ __launch_bounds__(256) void setup_kernel(PrepArgs a,
                                                    const float* feat,
                                                    const int* __restrict__ rcv,
                                                    ushort* __restrict__ wq,
                                                    ushort* __restrict__ featb,
                                                    uint* m_acc32,
                                                    int* __restrict__ hist,
                                                    ushort* __restrict__ ewq,
                                                    const float* __restrict__ e_w,
                                                    const float* __restrict__ px_out_w) {
  int i = blockIdx.x * 256 + threadIdx.x;          // i < 2,560,000 exactly
  float fv = feat[i];
  asm volatile("" ::: "memory");                   // feat read precedes m_acc zero
  featb[i] = f2b(fv);
  if (i < N_NODES * 64) m_acc32[i] = 0u;           // zero f16 m_acc (first 5.12 MB)
  if (i < N_EDGES) atomicAdd(&hist[rcv[i]], 1);    // hist zeroed by prior memset
  if (i < 9 * 16384) {
    int m = i >> 14, idx = i & 16383;
    int k = idx >> 7, n = idx & 127;
    wq[m * 16384 + n * 128 + k] = f2b(a.src[m][k * 128 + n]);
  }
  if (i < 4096) {                                  // ew table [0,2048), pw table [2048,4096)
    int t = i >> 11, idx = i & 2047, col = idx >> 7, k = idx & 127;
    float v = (col == 0) ? (t ? px_out_w[k] : e_w[k]) : 0.0f;
    ewq[i] = f2b(v);
  }
}

// ---------------- MFMA helpers ----------------
// 64 rows x 32 cols per wave; PAIRED columns: lane (c,q) owns cols n0+2c, n0+2c+1
__device__ __forceinline__ void gemm2(const ushort* X, const ushort* __restrict__ Wn0,
                                      int c, int q, f32x4 acc[4][2]) {
  const int kq = q * 8;
  bf16x8 b[2][4];
#pragma unroll
  for (int ct = 0; ct < 2; ++ct)
#pragma unroll
    for (int ks = 0; ks < 4; ++ks)
      b[ct][ks] = *(const bf16x8*)(Wn0 + (2 * c + ct) * 128 + ks * 32 + kq);
#pragma unroll
  for (int mt = 0; mt < 4; ++mt)
#pragma unroll
    for (int ks = 0; ks < 4; ++ks) {
      bf16x8 a = *(const bf16x8*)(X + (mt * 16 + c) * XS + ks * 32 + kq);
      acc[mt][0] = __builtin_amdgcn_mfma_f32_16x16x32_bf16(a, b[0][ks], acc[mt][0], 0, 0, 0);
      acc[mt][1] = __builtin_amdgcn_mfma_f32_16x16x32_bf16(a, b[1][ks], acc[mt][1], 0, 0, 0);
    }
}

// 16 rows x 32 cols per wave (classic c / c+16 mapping — used by precompute & node)
__device__ __forceinline__ void gemm1(const ushort* X, const ushort* __restrict__ Wn0,
                                      int c, int q, f32x4 acc[2]) {
  const int kq = q * 8;
#pragma unroll
  for (int ks = 0; ks < 4; ++ks) {
    bf16x8 a  = *(const bf16x8*)(X + c * XS + ks * 32 + kq);
    bf16x8 b0 = *(const bf16x8*)(Wn0 + c * 128 + ks * 32 + kq);
    bf16x8 b1 = *(const bf16x8*)(Wn0 + (16 + c) * 128 + ks * 32 + kq);
    acc[0] = __builtin_amdgcn_mfma_f32_16x16x32_bf16(a, b0, acc[0], 0, 0, 0);
    acc[1] = __builtin_amdgcn_mfma_f32_16x16x32_bf16(a, b1, acc[1], 0, 0, 0);
  }
}

// per-wave 16-row x 1-col dot (table col0 only nonzero; result on c==0 lanes)
__device__ __forceinline__ void gemm_dot16(const ushort* X, const ushort* __restrict__ T,
                                           int c, int q, f32x4* accd) {
  const int kq = q * 8;
#pragma unroll
  for (int ks = 0; ks < 4; ++ks) {
    bf16x8 bg = *(const bf16x8*)(T + c * 128 + ks * 32 + kq);
    bf16x8 a = *(const bf16x8*)(X + c * XS + ks * 32 + kq);
    *accd = __builtin_amdgcn_mfma_f32_16x16x32_bf16(a, bg, *accd, 0, 0, 0);
  }
}

__device__ __forceinline__ void stage_row16(ushort* X, const ushort* __restrict__ src,
                                            int row, int sub) {
  const bf16x8* s = (const bf16x8*)src;
  ((bf16x8*)(X + row * XS))[sub] = s[sub];
}

// ---------------- scan (block 0) || precompute P0/P1' + zero outv (blocks 1..1250) ----
__global__ __launch_bounds__(256, 4) void scanpre_kernel(
    const int* __restrict__ hist, int* __restrict__ cursor,
    const ushort* __restrict__ featb, const ushort* __restrict__ wq,
    const float* __restrict__ pe_b0,
    ushort* __restrict__ p0h, ushort* __restrict__ p1h,
    float* __restrict__ outv) {
  const int tid = threadIdx.x;

  if (blockIdx.x == 0) {                           // ---- scan role: 20000 bins ----
    __shared__ int sbuf[256];
    const int lo = tid * 79;                       // 256*79 = 20224 >= 20000
    int s = 0;
    for (int j = 0; j < 79; ++j) {
      int i = lo + j;
      if (i < N_NODES) s += hist[i];
    }
    sbuf[tid] = s;
    __syncthreads();
    for (int off = 1; off < 256; off <<= 1) {
      int t = (tid >= off) ? sbuf[tid - off] : 0;
      __syncthreads();
      sbuf[tid] += t;
      __syncthreads();
    }
    int run = sbuf[tid] - s;                       // exclusive prefix of this chunk
    for (int j = 0; j < 79; ++j) {
      int i = lo + j;
      if (i < N_NODES) { cursor[i] = run; run += hist[i]; }
    }
    return;
  }

  // ---- precompute role: 16 nodes/block ----
  __shared__ ushort XA[16 * XS];
  const int pblk = blockIdx.x - 1;
  const int nb0 = pblk * 16;
  const int lane = tid & 63;
  const int wv = tid >> 6;
  const int c = lane & 15, q = lane >> 4;
  const int n0 = wv * 32;
  const int col0 = n0 + c, col1 = col0 + 16;

  int gid = pblk * 256 + tid;                      // 1250*256 = 320000 >= 60000
  if (gid < 60000) outv[gid] = 0.0f;

  {
    int row = tid >> 4, sub = tid & 15;
    stage_row16(XA, featb + (size_t)(nb0 + row) * 128, row, sub);
  }
  BAR();

  const f32x4 z4 = {0.f, 0.f, 0.f, 0.f};
  f32x4 a2[2];
  a2[0] = z4; a2[1] = z4;
  gemm1(XA, wq + 0 * 16384 + n0 * 128, c, q, a2);
#pragma unroll
  for (int rg = 0; rg < 4; ++rg) {
    int nn = nb0 + q * 4 + rg;
    p0h[(size_t)nn * 128 + col0] = f2h(a2[0][rg]);
    p0h[(size_t)nn * 128 + col1] = f2h(a2[1][rg]);
  }
  a2[0] = z4; a2[1] = z4;
  gemm1(XA, wq + 1 * 16384 + n0 * 128, c, q, a2);
  float bb0 = pe_b0[col0], bb1 = pe_b0[col1];      // fold pe_b0 into P1'
#pragma unroll
  for (int rg = 0; rg < 4; ++rg) {
    int nn = nb0 + q * 4 + rg;
    p1h[(size_t)nn * 128 + col0] = f2h(a2[0][rg] + bb0);
    p1h[(size_t)nn * 128 + col1] = f2h(a2[1][rg] + bb1);
  }
}

__global__ __launch_bounds__(256) void scatter_kernel(const int* __restrict__ snd,
                                                      const int* __restrict__ rcv,
                                                      int* __restrict__ cursor,
                                                      uint* __restrict__ sedge) {
  int e = blockIdx.x * 256 + threadIdx.x;          // exact: 2500*256 = 640000
  int r = rcv[e];
  int p = atomicAdd(&cursor[r], 1);
  sedge[p] = (uint)snd[e] | ((uint)r << 16);       // both < 65536
}

// ---------------- edge kernel: sorted edges, 3 GEMMs + 2 distributed MFMA dots.
// Spill-free ordering: reduce (accm dies) BEFORE accx GEMM; in-place gating.
// launch_bounds(256,6): VGPR cap ~85 > ~64 peak live -> no scratch. ----
__global__ __launch_bounds__(256, 6) void edge_kernel(
    const float* __restrict__ pos,
    const ushort* __restrict__ p0h, const ushort* __restrict__ p1h,
    const uint* __restrict__ sedge,
    const ushort* __restrict__ wq, const ushort* __restrict__ ewq,
    const float* __restrict__ pe_w0,
    const float* __restrict__ pe_b1,
    const float* __restrict__ px_b0, const float* __restrict__ px_b1,
    const float* __restrict__ px_out_b, const float* __restrict__ e_b,
    float* __restrict__ outv, ushort* __restrict__ macc16) {
  __shared__ ushort XA[64 * XS];          // 17408 B
  __shared__ float sacc[64][4];
  __shared__ float lenf[64], pp[64], egl[64];
  __shared__ float vec3[64][3];
  __shared__ int segid[64];
  __shared__ int segrcv[64];
  __shared__ int nsegS;

  const int tid = threadIdx.x;
  const int base = blockIdx.x * 64;
  const int lane = tid & 63;
  const int wv = tid >> 6;
  const int c = lane & 15, q = lane >> 4;
  const int n0 = wv * 32;
  const int col0 = n0 + 2 * c, col1 = col0 + 1;   // paired columns

  ((float*)sacc)[tid] = 0.0f;

  if (tid < 64) {
    int r = (int)(sedge[base + tid] >> 16);
    int prev = (tid == 0) ? -1 : (int)(sedge[base + tid - 1] >> 16);
    bool bnd = (r != prev);
    unsigned long long bm = __ballot(bnd);
    int sid = (int)__popcll(bm << (63 - tid)) - 1;
    segid[tid] = sid;
    if (bnd) segrcv[sid] = r;
    if (tid == 0) nsegS = (int)__popcll(bm);
  }

  // ---- stage h0 = silu(P0[s] + P1'[r] + L*wL) ----
  {
    int row = tid >> 2, sub = tid & 3;
    uint v = sedge[base + row];
    int s = (int)(v & 0xffffu), r = (int)(v >> 16);
    float vx = pos[r * 3 + 0] - pos[s * 3 + 0];
    float vy = pos[r * 3 + 1] - pos[s * 3 + 1];
    float vz = pos[r * 3 + 2] - pos[s * 3 + 2];
    float n2 = vx * vx + vy * vy + vz * vz;
    float L = (n2 > 0.0f) ? sqrtf(n2) : 0.0f;
    if (sub == 0) {
      vec3[row][0] = vx; vec3[row][1] = vy; vec3[row][2] = vz;
      lenf[row] = L;
    }
    const int cb = sub * 32;
    const uint* a0 = (const uint*)(p0h + (size_t)s * 128) + sub * 16;
    const uint* a1 = (const uint*)(p1h + (size_t)r * 128) + sub * 16;
    const float* wL = pe_w0 + 256 * 128 + cb;
    uint* d = (uint*)(XA + row * XS + cb);
#pragma unroll
    for (int j = 0; j < 16; ++j) {
      uint u0 = a0[j], u1 = a1[j];
      float x = lo16f(u0) + lo16f(u1) + L * wL[2 * j];
      float y = hi16f(u0) + hi16f(u1) + L * wL[2 * j + 1];
      d[j] = cvt_pk_bf16(silu(x), silu(y));
    }
  }
  BAR();   // BAR1: XA=h0, seg labels, lenf/vec3 visible

  const int nseg = nsegS;
  const f32x4 z4 = {0.f, 0.f, 0.f, 0.f};

  // ---- phi_e layer 1: XA(h0) -> m ----
  f32x4 accm[4][2];
#pragma unroll
  for (int mt = 0; mt < 4; ++mt) { accm[mt][0] = z4; accm[mt][1] = z4; }
  gemm2(XA, wq + 2 * 16384 + n0 * 128, c, q, accm);
  {
    float b0 = pe_b1[col0], b1 = pe_b1[col1];
#pragma unroll
    for (int mt = 0; mt < 4; ++mt)
#pragma unroll
      for (int rg = 0; rg < 4; ++rg) {
        accm[mt][0][rg] = silu(accm[mt][0][rg] + b0);
        accm[mt][1][rg] = silu(accm[mt][1][rg] + b1);
      }
  }
  BAR();   // BAR2: all waves done reading h0
  {
#pragma unroll
    for (int mt = 0; mt < 4; ++mt)
#pragma unroll
      for (int rg = 0; rg < 4; ++rg) {
        int row = mt * 16 + q * 4 + rg;
        *(uint*)(XA + row * XS + col0) = cvt_pk_bf16(accm[mt][0][rg], accm[mt][1][rg]);
      }
  }
  BAR();   // BAR3: m visible

  // ---- gate via distributed MFMA dot (each wave its own 16 rows) ----
  {
    f32x4 accg = z4;
    gemm_dot16(XA + (wv * 16) * XS, ewq, c, q, &accg);
    if (c == 0) {
      float eb = e_b[0];
#pragma unroll
      for (int rg = 0; rg < 4; ++rg)
        egl[wv * 16 + q * 4 + rg] = sigmoid_fast(accg[rg] + eb);
    }
  }
  BAR();   // BAR4: egl (all quadrants) visible

  // ---- gate accm IN PLACE, segmented reduce, atomics; accm DIES here ----
  {
#pragma unroll
    for (int mt = 0; mt < 4; ++mt)
#pragma unroll
      for (int rg = 0; rg < 4; ++rg) {
        float eg = egl[mt * 16 + q * 4 + rg];
        accm[mt][0][rg] *= eg;
        accm[mt][1][rg] *= eg;
      }
    for (int sg = 0; sg < nseg; ++sg) {
      float t0 = 0.0f, t1 = 0.0f;
#pragma unroll
      for (int mt = 0; mt < 4; ++mt)
#pragma unroll
        for (int rg = 0; rg < 4; ++rg) {
          bool in = (segid[mt * 16 + q * 4 + rg] == sg);
          t0 += in ? accm[mt][0][rg] : 0.0f;
          t1 += in ? accm[mt][1][rg] : 0.0f;
        }
      t0 += __shfl_xor(t0, 16); t0 += __shfl_xor(t0, 32);
      t1 += __shfl_xor(t1, 16); t1 += __shfl_xor(t1, 32);
      if (q == 0) {
        ushort* dst = macc16 + (size_t)segrcv[sg] * 128;
        pk_atomic_f16(dst + col0, t0, t1);         // adjacent cols: one atomic
      }
    }
  }

  // ---- phi_x layer 0 (atomics above overlap this GEMM) ----
  f32x4 accx[4][2];
#pragma unroll
  for (int mt = 0; mt < 4; ++mt) { accx[mt][0] = z4; accx[mt][1] = z4; }
  gemm2(XA, wq + 3 * 16384 + n0 * 128, c, q, accx);
  BAR();   // BAR5: all waves done reading XA(m)
  {
    float b0 = px_b0[col0], b1 = px_b0[col1];
#pragma unroll
    for (int mt = 0; mt < 4; ++mt)
#pragma unroll
      for (int rg = 0; rg < 4; ++rg) {
        int row = mt * 16 + q * 4 + rg;
        *(uint*)(XA + row * XS + col0) = cvt_pk_bf16(silu(accx[mt][0][rg] + b0),
                                                     silu(accx[mt][1][rg] + b1));
      }
  }
  BAR();   // BAR6: px0 visible

  // ---- phi_x layer 1 ----
  f32x4 accy[4][2];
#pragma unroll
  for (int mt = 0; mt < 4; ++mt) { accy[mt][0] = z4; accy[mt][1] = z4; }
  gemm2(XA, wq + 4 * 16384 + n0 * 128, c, q, accy);
  BAR();   // BAR7: all waves done reading px0
  {
    float b0 = px_b1[col0], b1 = px_b1[col1];
#pragma unroll
    for (int mt = 0; mt < 4; ++mt)
#pragma unroll
      for (int rg = 0; rg < 4; ++rg) {
        int row = mt * 16 + q * 4 + rg;
        *(uint*)(XA + row * XS + col0) = cvt_pk_bf16(silu(accy[mt][0][rg] + b0),
                                                     silu(accy[mt][1][rg] + b1));
      }
  }
  BAR();   // BAR8: silu(px1) visible

  // ---- phi_x tail via distributed MFMA dot ----
  {
    f32x4 accp = z4;
    gemm_dot16(XA + (wv * 16) * XS, ewq + 2048, c, q, &accp);
    if (c == 0) {
#pragma unroll
      for (int rg = 0; rg < 4; ++rg)
        pp[wv * 16 + q * 4 + rg] = accp[rg];
    }
  }
  BAR();   // BAR9: pp visible

  if (tid < 192) {
    int ee = tid / 3, cc = tid - ee * 3;
    float phi = pp[ee] + px_out_b[0];
    float sh = phi * vec3[ee][cc] * __builtin_amdgcn_rcpf(1.0f + lenf[ee]);
    atomicAdd(&sacc[segid[ee]][cc], sh);
  }
  BAR();   // BAR10: sacc complete
  if (tid < nseg * 3) {
    int sg = tid / 3, cc = tid - sg * 3;
    atomicAdd(&outv[(size_t)segrcv[sg] * 3 + cc], sacc[sg][cc]);
  }
}

// ---------------- node kernel: 16-node tiles (1250 blocks), f16 m_acc in ----------------
__global__ __launch_bounds__(256, 5) void node_kernel(
    const float* __restrict__ pos,
    const ushort* __restrict__ featb, const ushort* __restrict__ wq,
    const ushort* __restrict__ outm,
    const float* __restrict__ ph_b0, const float* __restrict__ ph_b1,
    const float* __restrict__ ph_b2,
    float* __restrict__ outv, float* __restrict__ outf) {
  __shared__ ushort XA[16 * XS];
  __shared__ ushort XB[16 * XS];

  const int tid = threadIdx.x;
  const int nb0 = blockIdx.x * 16;      // 1250*16 = 20000 exact
  const int lane = tid & 63;
  const int wv = tid >> 6;
  const int c = lane & 15, q = lane >> 4;
  const int n0 = wv * 32;
  const int col0 = n0 + c, col1 = col0 + 16;

  {
    int row = tid >> 4, sub = tid & 15;   // 16 threads/row
    int nn = nb0 + row;
    const uint* s4 = (const uint*)(outm + (size_t)nn * 128) + sub * 4;
    uint* d = (uint*)(XA + row * XS) + sub * 4;
#pragma unroll
    for (int j = 0; j < 4; ++j) {
      uint u = s4[j];
      d[j] = cvt_pk_bf16(lo16f(u) * INV_SQRT_AVG, hi16f(u) * INV_SQRT_AVG);
    }
    stage_row16(XB, featb + (size_t)nn * 128, row, sub);
  }
  BAR();

  const f32x4 z4 = {0.f, 0.f, 0.f, 0.f};
  f32x4 a2[2];
  a2[0] = z4; a2[1] = z4;

  // ---- ph layer 0: [m_i | feat] ----
  gemm1(XA, wq + 5 * 16384 + n0 * 128, c, q, a2);
  gemm1(XB, wq + 6 * 16384 + n0 * 128, c, q, a2);
  BAR();
  {
    float b0 = ph_b0[col0], b1 = ph_b0[col1];
#pragma unroll
    for (int rg = 0; rg < 4; ++rg) {
      int row = q * 4 + rg;
      uint u = cvt_pk_bf16(silu(a2[0][rg] + b0), silu(a2[1][rg] + b1));
      XA[row * XS + col0] = (ushort)u;
      XA[row * XS + col1] = (ushort)(u >> 16);
    }
  }
  BAR();

  // ---- ph layer 1 ----
  a2[0] = z4; a2[1] = z4;
  gemm1(XA, wq + 7 * 16384 + n0 * 128, c, q, a2);
  BAR();
  {
    float b0 = ph_b1[col0], b1 = ph_b1[col1];
#pragma unroll
    for (int rg = 0; rg < 4; ++rg) {
      int row = q * 4 + rg;
      uint u = cvt_pk_bf16(silu(a2[0][rg] + b0), silu(a2[1][rg] + b1));
      XA[row * XS + col0] = (ushort)u;
      XA[row * XS + col1] = (ushort)(u >> 16);
    }
  }
  BAR();

  // ---- ph layer 2 (no act) + residual from XB(featb) ----
  a2[0] = z4; a2[1] = z4;
  gemm1(XA, wq + 8 * 16384 + n0 * 128, c, q, a2);
  {
    float b0 = ph_b2[col0], b1 = ph_b2[col1];
#pragma unroll
    for (int rg = 0; rg < 4; ++rg) {
      int row = q * 4 + rg;
      size_t o = (size_t)(nb0 + row) * 128;
      float r0 = b2f(XB[row * XS + col0]);
      float r1 = b2f(XB[row * XS + col1]);
      outf[o + col0] = a2[0][rg] + b0 + r0;
      outf[o + col1] = a2[1][rg] + b1 + r1;
    }
  }
  if (tid < 48) {
    int nl = tid / 3, cc = tid - nl * 3;
    int nn = nb0 + nl;
    outv[nn * 3 + cc] = pos[nn * 3 + cc] + outv[nn * 3 + cc] * INV_AVG;
  }
}

// ---------------- launch ----------------
extern "C" void kernel_launch(void* const* d_in, const int* in_sizes, int n_in,
                              void* d_out, int out_size, void* d_ws, size_t ws_size,
                              hipStream_t stream) {
  const float* pos  = (const float*)d_in[0];
  const float* feat = (const float*)d_in[1];
  const float* pe_w0 = (const float*)d_in[2];
  const float* pe_b0 = (const float*)d_in[3];
  const float* pe_b1 = (const float*)d_in[5];
  const float* px_b0 = (const float*)d_in[7];
  const float* px_b1 = (const float*)d_in[9];
  const float* px_out_w = (const float*)d_in[10];
  const float* px_out_b = (const float*)d_in[11];
  const float* e_w = (const float*)d_in[12];
  const float* e_b = (const float*)d_in[13];
  const float* ph_b0 = (const float*)d_in[15];
  const float* ph_b1 = (const float*)d_in[17];
  const float* ph_b2 = (const float*)d_in[19];
  const int* snd = (const int*)d_in[20];
  const int* rcv = (const int*)d_in[21];

  // d_ws: wq + featb (5.41 MB — proven footprint)
  ushort* wq = (ushort*)d_ws;
  ushort* featb = wq + FEATB_OFF;

  // d_in[1]: [0,5.12MB) f16 m_acc; [5.12,10.24) P0 (f16)
  ushort* macc16 = (ushort*)d_in[1];
  ushort* p0h    = macc16 + 2560000;

  float* out  = (float*)d_out;
  float* outf = out + 60000;
  // outf scratch (dead before node output overwrites it):
  //   sedge 2.56MB | p1h 5.12MB | hist 80KB | cursor 80KB | ewq 8KB = 7.85MB
  uint*   sedge  = (uint*)outf;
  ushort* p1h    = (ushort*)(sedge + N_EDGES);
  int*    hist   = (int*)(p1h + 2560000);
  int*    cursor = hist + N_NODES;
  ushort* ewq    = (ushort*)(cursor + N_NODES);

  PrepArgs a;
  a.src[0] = pe_w0;
  a.src[1] = pe_w0 + 128 * 128;
  a.src[2] = (const float*)d_in[4];               // pe_w1
  a.src[3] = (const float*)d_in[6];               // px_w0
  a.src[4] = (const float*)d_in[8];               // px_w1
  a.src[5] = (const float*)d_in[14];              // ph_w0 (m_i half)
  a.src[6] = (const float*)d_in[14] + 128 * 128;  // ph_w0 (feat half)
  a.src[7] = (const float*)d_in[16];              // ph_w1
  a.src[8] = (const float*)d_in[18];              // ph_w2

  hipMemsetAsync(hist, 0, N_NODES * sizeof(int), stream);

  setup_kernel<<<(N_NODES * 128) / 256, 256, 0, stream>>>(
      a, feat, rcv, wq, featb, (uint*)macc16, hist, ewq, e_w, px_out_w);

  // scan (block 0) || precompute P0/P1' + zero outv (blocks 1..1250)
  scanpre_kernel<<<1251, 256, 0, stream>>>(hist, cursor, featb, wq, pe_b0,
                                           p0h, p1h, out);

  scatter_kernel<<<N_EDGES / 256, 256, 0, stream>>>(snd, rcv, cursor, sedge);

  edge_kernel<<<N_EDGES / 64, 256, 0, stream>>>(
      pos, p0h, p1h, sedge, wq, ewq,
      pe_w0, pe_b1, px_b0, px_b1, px_out_b, e_b,
      out, macc16);

  node_kernel<<<N_NODES / 16, 256, 0, stream>>>(
      pos, featb, wq, macc16, ph_b0, ph_b1, ph_b2,
      out, outf);
}